// Round 15
// baseline (235.300 us; speedup 1.0000x reference)
//
#include <hip/hip_runtime.h>
#include <math.h>

#define TWO_PI 6.283185307179586f

typedef __attribute__((ext_vector_type(8))) short bf16x8;
typedef __attribute__((ext_vector_type(4))) short bf16x4;
typedef __attribute__((ext_vector_type(4))) float f32x4;
typedef __attribute__((ext_vector_type(4))) _Float16 h16x4;
typedef __attribute__((ext_vector_type(8))) _Float16 h16x8;

__device__ __forceinline__ short f2bf(float f) {
    unsigned u = __float_as_uint(f);
    unsigned r = (u + 0x7FFFu + ((u >> 16) & 1u)) >> 16;   // RNE
    return (short)r;
}
__device__ __forceinline__ float bf2f(short s) {
    return __uint_as_float(((unsigned)(unsigned short)s) << 16);
}

// base-4 digit reversal of a 6-bit index (radix-4 FFT output order)
__device__ __forceinline__ int dr4(int s) {
    return ((s & 3) << 4) | (s & 12) | ((s >> 4) & 3);
}

__device__ __forceinline__ void cmulw(float& xr, float& xi, float wr, float wi) {
    const float tr = xr * wr - xi * wi;
    xi = xr * wi + xi * wr;
    xr = tr;
}

// ---- bf16x4 LDS helpers (fp32 compute, bf16 storage) ----
__device__ __forceinline__ f32x4 ld4bf(const char* Z, int off) {
    const bf16x4 v = *(const bf16x4*)(Z + off);
    f32x4 r;
    r[0] = bf2f(v[0]); r[1] = bf2f(v[1]); r[2] = bf2f(v[2]); r[3] = bf2f(v[3]);
    return r;
}
__device__ __forceinline__ void st4bf(char* Z, int off, f32x4 a) {
    bf16x4 v;
    v[0] = f2bf(a[0]); v[1] = f2bf(a[1]); v[2] = f2bf(a[2]); v[3] = f2bf(a[3]);
    *(bf16x4*)(Z + off) = v;
}

// ---------------------------------------------------------------------------
// One radix-4 stage on a swizzled bf16 tile (2 planes x 64 slots x 256B).
// Tile layout: plane p at Z + p*16384; row r at r*256; logical channel byte
// cb accessed at (cb ^ ((r&7)<<4)). cb = 8B-aligned (4-ch groups).
// Stage formulas identical to the HW-verified rounds 8-14.
// ---------------------------------------------------------------------------
__device__ __forceinline__ int swzoff(int r, int cb) {
    return r * 256 + (cb ^ ((r & 7) << 4));
}

__device__ __forceinline__ void dif_stage_bf(char* Z, const float* wtr, const float* wti,
                                             int cb, int h, int s) {
    const int q  = 16 >> (2 * s);
    const int tw = 1 << (2 * s);
    const int j = h & (q - 1);
    const int g = (s == 0) ? 0 : (h >> (4 - 2 * s));
    const int i0 = g * (q << 2) + j;
    const int i1 = i0 + q, i2 = i1 + q, i3 = i2 + q;
    const int o0 = swzoff(i0, cb), o1 = swzoff(i1, cb);
    const int o2 = swzoff(i2, cb), o3 = swzoff(i3, cb);
    const f32x4 a0r = ld4bf(Z, o0), a0i = ld4bf(Z + 16384, o0);
    const f32x4 a1r = ld4bf(Z, o1), a1i = ld4bf(Z + 16384, o1);
    const f32x4 a2r = ld4bf(Z, o2), a2i = ld4bf(Z + 16384, o2);
    const f32x4 a3r = ld4bf(Z, o3), a3i = ld4bf(Z + 16384, o3);
    const int m = j * tw;
    const float w1r = wtr[m],     w1i = wti[m];
    const float w2r = wtr[2 * m], w2i = wti[2 * m];
    const float w3r = wtr[3 * m], w3i = wti[3 * m];
    f32x4 O0r, O0i, O1r, O1i, O2r, O2i, O3r, O3i;
#pragma unroll
    for (int e = 0; e < 4; ++e) {
        const float t0r = a0r[e] + a2r[e], t0i = a0i[e] + a2i[e];
        const float t2r = a0r[e] - a2r[e], t2i = a0i[e] - a2i[e];
        const float t1r = a1r[e] + a3r[e], t1i = a1i[e] + a3i[e];
        const float dr  = a1r[e] - a3r[e], di  = a1i[e] - a3i[e];
        const float t3r = di, t3i = -dr;                 // -i*(a1-a3)
        O0r[e] = t0r + t1r;  O0i[e] = t0i + t1i;
        float y1r = t2r + t3r, y1i = t2i + t3i;
        float y2r = t0r - t1r, y2i = t0i - t1i;
        float y3r = t2r - t3r, y3i = t2i - t3i;
        if (m) {
            cmulw(y1r, y1i, w1r, w1i);
            cmulw(y2r, y2i, w2r, w2i);
            cmulw(y3r, y3i, w3r, w3i);
        }
        O1r[e] = y1r; O1i[e] = y1i;
        O2r[e] = y2r; O2i[e] = y2i;
        O3r[e] = y3r; O3i[e] = y3i;
    }
    st4bf(Z, o0, O0r);  st4bf(Z + 16384, o0, O0i);
    st4bf(Z, o1, O1r);  st4bf(Z + 16384, o1, O1i);
    st4bf(Z, o2, O2r);  st4bf(Z + 16384, o2, O2i);
    st4bf(Z, o3, O3r);  st4bf(Z + 16384, o3, O3i);
}

__device__ __forceinline__ void dit_stage_bf(char* Z, const float* wtr, const float* wti,
                                             int cb, int h, int s) {
    const int q  = 16 >> (2 * s);
    const int tw = 1 << (2 * s);
    const int j = h & (q - 1);
    const int g = (s == 0) ? 0 : (h >> (4 - 2 * s));
    const int i0 = g * (q << 2) + j;
    const int i1 = i0 + q, i2 = i1 + q, i3 = i2 + q;
    const int o0 = swzoff(i0, cb), o1 = swzoff(i1, cb);
    const int o2 = swzoff(i2, cb), o3 = swzoff(i3, cb);
    const f32x4 a0r = ld4bf(Z, o0), a0i = ld4bf(Z + 16384, o0);
    const f32x4 a1r = ld4bf(Z, o1), a1i = ld4bf(Z + 16384, o1);
    const f32x4 a2r = ld4bf(Z, o2), a2i = ld4bf(Z + 16384, o2);
    const f32x4 a3r = ld4bf(Z, o3), a3i = ld4bf(Z + 16384, o3);
    const int m = j * tw;
    const float w1r = wtr[m],     w1i = -wti[m];         // conj
    const float w2r = wtr[2 * m], w2i = -wti[2 * m];
    const float w3r = wtr[3 * m], w3i = -wti[3 * m];
    f32x4 O0r, O0i, O1r, O1i, O2r, O2i, O3r, O3i;
#pragma unroll
    for (int e = 0; e < 4; ++e) {
        float b1r = a1r[e], b1i = a1i[e];
        float b2r = a2r[e], b2i = a2i[e];
        float b3r = a3r[e], b3i = a3i[e];
        if (m) {
            cmulw(b1r, b1i, w1r, w1i);
            cmulw(b2r, b2i, w2r, w2i);
            cmulw(b3r, b3i, w3r, w3i);
        }
        const float u0r = a0r[e] + b2r, u0i = a0i[e] + b2i;
        const float u1r = a0r[e] - b2r, u1i = a0i[e] - b2i;
        const float u2r = b1r + b3r,    u2i = b1i + b3i;
        const float dr  = b1r - b3r,    di  = b1i - b3i;
        const float u3r = -di, u3i = dr;                 // +i*(b1-b3)
        O0r[e] = u0r + u2r; O0i[e] = u0i + u2i;
        O1r[e] = u1r + u3r; O1i[e] = u1i + u3i;
        O2r[e] = u0r - u2r; O2i[e] = u0i - u2i;
        O3r[e] = u1r - u3r; O3i[e] = u1i - u3i;
    }
    st4bf(Z, o0, O0r);  st4bf(Z + 16384, o0, O0i);
    st4bf(Z, o1, O1r);  st4bf(Z + 16384, o1, O1i);
    st4bf(Z, o2, O2r);  st4bf(Z + 16384, o2, O2i);
    st4bf(Z, o3, O3r);  st4bf(Z + 16384, o3, O3i);
}

// ---------------------------------------------------------------------------
// global_load_lds staging of one (b, dg, ct) tile: 2 planes x 64 slots x
// 256B (4 blks x 32ch x bf16), 2048 x 16B chunks. LDS dest LINEAR; T2
// swizzle applied via inverse-permuted GLOBAL chunk index (rule 21).
// ---------------------------------------------------------------------------
__device__ __forceinline__ void stage_ztile(const short* __restrict__ zre,
                                            const short* __restrict__ zim,
                                            char* Zbuf, int b, int dg, int ct,
                                            int wave, int lane) {
#pragma unroll
    for (int it = 0; it < 4; ++it) {
        const int q = wave * 256 + it * 64 + lane;   // 0..2047
        const int p = q >> 10;
        const int r = q & 1023;
        const int slot = r >> 4;
        const int c = r & 15;
        const int c_log = c ^ (slot & 7);
        const int blk = c_log >> 2, cj = c_log & 3;
        const short* src = p ? zim : zre;
        const size_t g = ((size_t)(b * 4096 + dg * 64 + slot) * 512)
                       + (size_t)(blk * 128 + ct * 32 + cj * 8);
        unsigned* lp = (unsigned*)(Zbuf + (wave * 4096 + it * 1024));  // uniform
        __builtin_amdgcn_global_load_lds((const unsigned*)(src + g), lp, 16, 0, 0);
    }
}

#define DECODE_BCT() \
    const int b  = blockIdx.x >> 8; \
    const int dg = (blockIdx.x >> 2) & 63; \
    const int ct = blockIdx.x & 3;

#define GADDR(slot, blk, f4) \
    (((size_t)(b * 4096 + (slot)) * 512) + (size_t)((blk) * 128 + ct * 32 + (f4) * 4))

#define GADDR8(slot, blk, e8) \
    (((size_t)(b * 4096 + (slot)) * 512) + (size_t)((blk) * 128 + ct * 32 + (e8) * 8))

#define SETUP_TABLE48() \
    if (tid < 48) { \
        float s_, c_; \
        sincosf(TWO_PI * (float)tid / 64.0f, &s_, &c_); \
        wre[tid] = c_; wim[tid] = -s_; \
    }

// ---- forward pass A: FFT over n1 (slots 64*n1+dg), twiddle, x fp32 -> z bf16
// (unchanged from the passing round-14 kernel: fp16 LDS, 512 threads)
extern "C" __global__ void __launch_bounds__(512)
fft_fwd_a(const float* __restrict__ x, short* __restrict__ zre, short* __restrict__ zim) {
    __shared__ __align__(16) _Float16 Lre[64][136];
    __shared__ __align__(16) _Float16 Lim[64][136];
    __shared__ float wre[48], wim[48];
    __shared__ float twr[64], twi[64];
    const int tid = threadIdx.x;
    SETUP_TABLE48();
    DECODE_BCT();   // dg = n2
    if (tid >= 64 && tid < 128) {
        const int s1 = tid - 64;
        float sn, cs;
        sincosf(-(TWO_PI / 4096.0f) * (float)(dg * dr4(s1)), &sn, &cs);
        twr[s1] = cs; twi[s1] = sn;
    }
    for (int idx = tid; idx < 2048; idx += 512) {
        const int n1 = idx >> 5, q = idx & 31, blk = q >> 3, f4 = q & 7;
        const int cl = blk * 32 + f4 * 4;
        const float4 v = *(const float4*)(x + GADDR(n1 * 64 + dg, blk, f4));
        h16x4 hv, hz;
        hv[0] = (_Float16)v.x; hv[1] = (_Float16)v.y;
        hv[2] = (_Float16)v.z; hv[3] = (_Float16)v.w;
        hz[0] = (_Float16)0.f; hz[1] = (_Float16)0.f;
        hz[2] = (_Float16)0.f; hz[3] = (_Float16)0.f;
        *(h16x4*)&Lre[n1][cl] = hv;
        *(h16x4*)&Lim[n1][cl] = hz;
    }
    // radix-4 DIF, fp16 LDS, channel-vectorized (proven round-14 core)
    {
        const int c4 = (tid & 31) * 4;
        const int h = tid >> 5;
#pragma unroll
        for (int s = 0; s < 3; ++s) {
            const int q  = 16 >> (2 * s);
            const int tw = 1 << (2 * s);
            __syncthreads();
            const int j = h & (q - 1);
            const int g = (s == 0) ? 0 : (h >> (4 - 2 * s));
            const int i0 = g * (q << 2) + j;
            const int i1 = i0 + q, i2 = i1 + q, i3 = i2 + q;
            const h16x4 A0r = *(const h16x4*)&Lre[i0][c4], A0i = *(const h16x4*)&Lim[i0][c4];
            const h16x4 A1r = *(const h16x4*)&Lre[i1][c4], A1i = *(const h16x4*)&Lim[i1][c4];
            const h16x4 A2r = *(const h16x4*)&Lre[i2][c4], A2i = *(const h16x4*)&Lim[i2][c4];
            const h16x4 A3r = *(const h16x4*)&Lre[i3][c4], A3i = *(const h16x4*)&Lim[i3][c4];
            const int m = j * tw;
            const float w1r = wre[m],     w1i = wim[m];
            const float w2r = wre[2 * m], w2i = wim[2 * m];
            const float w3r = wre[3 * m], w3i = wim[3 * m];
            h16x4 O0r, O0i, O1r, O1i, O2r, O2i, O3r, O3i;
#pragma unroll
            for (int e = 0; e < 4; ++e) {
                const float a0r = (float)A0r[e], a0i = (float)A0i[e];
                const float a1r = (float)A1r[e], a1i = (float)A1i[e];
                const float a2r = (float)A2r[e], a2i = (float)A2i[e];
                const float a3r = (float)A3r[e], a3i = (float)A3i[e];
                const float t0r = a0r + a2r, t0i = a0i + a2i;
                const float t2r = a0r - a2r, t2i = a0i - a2i;
                const float t1r = a1r + a3r, t1i = a1i + a3i;
                const float dr  = a1r - a3r, di  = a1i - a3i;
                const float t3r = di, t3i = -dr;
                O0r[e] = (_Float16)(t0r + t1r);  O0i[e] = (_Float16)(t0i + t1i);
                float y1r = t2r + t3r, y1i = t2i + t3i;
                float y2r = t0r - t1r, y2i = t0i - t1i;
                float y3r = t2r - t3r, y3i = t2i - t3i;
                if (m) {
                    cmulw(y1r, y1i, w1r, w1i);
                    cmulw(y2r, y2i, w2r, w2i);
                    cmulw(y3r, y3i, w3r, w3i);
                }
                O1r[e] = (_Float16)y1r; O1i[e] = (_Float16)y1i;
                O2r[e] = (_Float16)y2r; O2i[e] = (_Float16)y2i;
                O3r[e] = (_Float16)y3r; O3i[e] = (_Float16)y3i;
            }
            *(h16x4*)&Lre[i0][c4] = O0r;  *(h16x4*)&Lim[i0][c4] = O0i;
            *(h16x4*)&Lre[i1][c4] = O1r;  *(h16x4*)&Lim[i1][c4] = O1i;
            *(h16x4*)&Lre[i2][c4] = O2r;  *(h16x4*)&Lim[i2][c4] = O2i;
            *(h16x4*)&Lre[i3][c4] = O3r;  *(h16x4*)&Lim[i3][c4] = O3i;
        }
        __syncthreads();
    }
    for (int idx = tid; idx < 2048; idx += 512) {
        const int s1 = idx >> 5, q = idx & 31, blk = q >> 3, f4 = q & 7;
        const int cl = blk * 32 + f4 * 4;
        const float cs = twr[s1], sn = twi[s1];
        const h16x4 hr = *(const h16x4*)&Lre[s1][cl];
        const h16x4 hi = *(const h16x4*)&Lim[s1][cl];
        bf16x4 pr, pi;
#pragma unroll
        for (int i = 0; i < 4; ++i) {
            const float vr = (float)hr[i], vi = (float)hi[i];
            pr[i] = f2bf(vr * cs - vi * sn);
            pi[i] = f2bf(vr * sn + vi * cs);
        }
        const size_t g = GADDR(s1 * 64 + dg, blk, f4);
        *(bf16x4*)(zre + g) = pr;
        *(bf16x4*)(zim + g) = pi;
    }
}

// ---------------------------------------------------------------------------
// forward pass B, REBUILT mlp-style: grid 512 (bh,dg,ct), MITER=4 over b,
// global_load_lds staging, double-buffered bf16 tiles, pure-copy store.
// Per tile: 3 DIF stages + fused fft4/scale sweep + store.
// ---------------------------------------------------------------------------
extern "C" __global__ void __launch_bounds__(512)
fft_fwd_b(short* __restrict__ zre, short* __restrict__ zim) {
    __shared__ __align__(16) char Zs[2][32768];
    __shared__ float wre[48], wim[48];
    const int tid = threadIdx.x;
    SETUP_TABLE48();
    const int bh = blockIdx.x >> 8;            // 0..1
    const int dg = (blockIdx.x >> 2) & 63;     // s1
    const int ct = blockIdx.x & 3;
    const int wave = tid >> 6, lane = tid & 63;
    const int cb = (tid & 31) * 8;             // butterfly: 4-ch byte base
    const int h  = tid >> 5;                   // butterfly index 0..15

    stage_ztile(zre, zim, Zs[0], bh * 4, dg, ct, wave, lane);

    for (int t = 0; t < 4; ++t) {
        __syncthreads();   // tile t staged (vmcnt drained); iter t-1 fully done
        if (t + 1 < 4)
            stage_ztile(zre, zim, Zs[(t + 1) & 1], bh * 4 + t + 1, dg, ct, wave, lane);

        char* Z = Zs[t & 1];
        dif_stage_bf(Z, wre, wim, cb, h, 0);
        __syncthreads();
        dif_stage_bf(Z, wre, wim, cb, h, 1);
        __syncthreads();
        dif_stage_bf(Z, wre, wim, cb, h, 2);
        __syncthreads();

        // fused fft4 across blocks + 1/128, in place (512 items, 1/thread)
        {
            const int slot = tid >> 3, jg4 = tid & 7;
            const int jb = jg4 * 8;                       // 4-ch byte offset in 32-ch window
            f32x4 r[4], m[4];
#pragma unroll
            for (int b4 = 0; b4 < 4; ++b4) {
                const int off = swzoff(slot, b4 * 64 + jb);
                r[b4] = ld4bf(Z, off);
                m[b4] = ld4bf(Z + 16384, off);
            }
            const float sc = 1.0f / 128.0f;
            f32x4 yr[4], ym[4];
#pragma unroll
            for (int e = 0; e < 4; ++e) {
                const float r0 = r[0][e], r1 = r[1][e], r2 = r[2][e], r3 = r[3][e];
                const float m0 = m[0][e], m1 = m[1][e], m2 = m[2][e], m3 = m[3][e];
                yr[0][e] = (r0 + r1 + r2 + r3) * sc;  ym[0][e] = (m0 + m1 + m2 + m3) * sc;
                yr[1][e] = (r0 + m1 - r2 - m3) * sc;  ym[1][e] = (m0 - r1 - m2 + r3) * sc;
                yr[2][e] = (r0 - r1 + r2 - r3) * sc;  ym[2][e] = (m0 - m1 + m2 - m3) * sc;
                yr[3][e] = (r0 - m1 - r2 + m3) * sc;  ym[3][e] = (m0 + r1 - m2 - r3) * sc;
            }
#pragma unroll
            for (int b4 = 0; b4 < 4; ++b4) {
                const int off = swzoff(slot, b4 * 64 + jb);
                st4bf(Z, off, yr[b4]);
                st4bf(Z + 16384, off, ym[b4]);
            }
        }
        __syncthreads();

        // store: LDS -> global, pure 16B copies with de-swizzle
        const int b = bh * 4 + t;
#pragma unroll
        for (int kq = 0; kq < 4; ++kq) {
            const int q = wave * 256 + kq * 64 + lane;
            const int p = q >> 10;
            const int r2 = q & 1023;
            const int slot = r2 >> 4;
            const int c = r2 & 15;
            const int c_log = c ^ (slot & 7);
            const int blk = c_log >> 2, cj = c_log & 3;
            const bf16x8 v = *(const bf16x8*)(Z + q * 16);
            short* dst = p ? zim : zre;
            const size_t g = ((size_t)(b * 4096 + dg * 64 + slot) * 512)
                           + (size_t)(blk * 128 + ct * 32 + cj * 8);
            *(bf16x8*)(dst + g) = v;
        }
    }
}

// ---------------------------------------------------------------------------
// inverse pass A, REBUILT mlp-style: ifft4+scale sweep, 3 DIT stages,
// twiddle+store sweep. Same staging/pipelining as fft_fwd_b.
// ---------------------------------------------------------------------------
extern "C" __global__ void __launch_bounds__(512)
fft_inv_a(short* __restrict__ zre, short* __restrict__ zim) {
    __shared__ __align__(16) char Zs[2][32768];
    __shared__ float wre[48], wim[48];
    __shared__ float twr[64], twi[64];
    const int tid = threadIdx.x;
    SETUP_TABLE48();
    const int bh = blockIdx.x >> 8;
    const int dg = (blockIdx.x >> 2) & 63;     // s1
    const int ct = blockIdx.x & 3;
    if (tid >= 64 && tid < 128) {
        const int n2 = tid - 64;
        float sn, cs;
        sincosf((TWO_PI / 4096.0f) * (float)(n2 * dr4(dg)), &sn, &cs);
        twr[n2] = cs; twi[n2] = sn;
    }
    const int wave = tid >> 6, lane = tid & 63;
    const int cb = (tid & 31) * 8;
    const int h  = tid >> 5;

    stage_ztile(zre, zim, Zs[0], bh * 4, dg, ct, wave, lane);

    for (int t = 0; t < 4; ++t) {
        __syncthreads();
        if (t + 1 < 4)
            stage_ztile(zre, zim, Zs[(t + 1) & 1], bh * 4 + t + 1, dg, ct, wave, lane);

        char* Z = Zs[t & 1];

        // fused inverse fft4 + 1/128, in place (512 items, 1/thread)
        {
            const int slot = tid >> 3, jg4 = tid & 7;
            const int jb = jg4 * 8;
            f32x4 r[4], m[4];
#pragma unroll
            for (int b4 = 0; b4 < 4; ++b4) {
                const int off = swzoff(slot, b4 * 64 + jb);
                r[b4] = ld4bf(Z, off);
                m[b4] = ld4bf(Z + 16384, off);
            }
            const float sc = 1.0f / 128.0f;
            f32x4 yr[4], ym[4];
#pragma unroll
            for (int e = 0; e < 4; ++e) {
                const float r0 = r[0][e], r1 = r[1][e], r2 = r[2][e], r3 = r[3][e];
                const float m0 = m[0][e], m1 = m[1][e], m2 = m[2][e], m3 = m[3][e];
                yr[0][e] = (r0 + r1 + r2 + r3) * sc;  ym[0][e] = (m0 + m1 + m2 + m3) * sc;
                yr[1][e] = (r0 - m1 - r2 + m3) * sc;  ym[1][e] = (m0 + r1 - m2 - r3) * sc;
                yr[2][e] = (r0 - r1 + r2 - r3) * sc;  ym[2][e] = (m0 - m1 + m2 - m3) * sc;
                yr[3][e] = (r0 + m1 - r2 - m3) * sc;  ym[3][e] = (m0 - r1 - m2 + r3) * sc;
            }
#pragma unroll
            for (int b4 = 0; b4 < 4; ++b4) {
                const int off = swzoff(slot, b4 * 64 + jb);
                st4bf(Z, off, yr[b4]);
                st4bf(Z + 16384, off, ym[b4]);
            }
        }
        __syncthreads();
        dit_stage_bf(Z, wre, wim, cb, h, 2);
        __syncthreads();
        dit_stage_bf(Z, wre, wim, cb, h, 1);
        __syncthreads();
        dit_stage_bf(Z, wre, wim, cb, h, 0);
        __syncthreads();

        // twiddle + store: 1024 (slot, chunk) pairs, 2/thread (both planes)
        const int b = bh * 4 + t;
#pragma unroll
        for (int k = 0; k < 2; ++k) {
            const int idx = tid + k * 512;
            const int slot = idx >> 4;
            const int c = idx & 15;
            const int c_log = c ^ (slot & 7);
            const int blk = c_log >> 2, cj = c_log & 3;
            const bf16x8 vr = *(const bf16x8*)(Z + slot * 256 + c * 16);
            const bf16x8 vi = *(const bf16x8*)(Z + 16384 + slot * 256 + c * 16);
            const float cs = twr[slot], sn = twi[slot];
            bf16x8 pr, pi;
#pragma unroll
            for (int i = 0; i < 8; ++i) {
                const float ar = bf2f(vr[i]), ai = bf2f(vi[i]);
                pr[i] = f2bf(ar * cs - ai * sn);
                pi[i] = f2bf(ar * sn + ai * cs);
            }
            const size_t g = ((size_t)(b * 4096 + dg * 64 + slot) * 512)
                           + (size_t)(blk * 128 + ct * 32 + cj * 8);
            *(bf16x8*)(zre + g) = pr;
            *(bf16x8*)(zim + g) = pi;
        }
    }
}

// ---- inverse pass B: inverse FFT over k1, write REAL fp32 into d_out
// (unchanged from the passing round-14 kernel: fp16 LDS)
extern "C" __global__ void __launch_bounds__(512)
fft_inv_b(const short* __restrict__ zre, const short* __restrict__ zim,
          float* __restrict__ out) {
    __shared__ __align__(16) _Float16 Lre[64][136];
    __shared__ __align__(16) _Float16 Lim[64][136];
    __shared__ float wre[48], wim[48];
    const int tid = threadIdx.x;
    SETUP_TABLE48();
    DECODE_BCT();   // dg = n2
    for (int idx = tid; idx < 1024; idx += 512) {
        const int s1 = idx >> 4, q = idx & 15, blk = q >> 2, e8 = q & 3;
        const int cl = blk * 32 + e8 * 8;
        const size_t g = GADDR8(s1 * 64 + dg, blk, e8);
        const bf16x8 vr = *(const bf16x8*)(zre + g);
        const bf16x8 vi = *(const bf16x8*)(zim + g);
        h16x8 hr, hi;
#pragma unroll
        for (int i = 0; i < 8; ++i) {
            hr[i] = (_Float16)bf2f(vr[i]);
            hi[i] = (_Float16)bf2f(vi[i]);
        }
        *(h16x8*)&Lre[s1][cl] = hr;
        *(h16x8*)&Lim[s1][cl] = hi;
    }
    // radix-4 DIT inverse, fp16 LDS, channel-vectorized (proven round-14 core)
    {
        const int c4 = (tid & 31) * 4;
        const int h = tid >> 5;
#pragma unroll
        for (int s = 2; s >= 0; --s) {
            const int q  = 16 >> (2 * s);
            const int tw = 1 << (2 * s);
            __syncthreads();
            const int j = h & (q - 1);
            const int g = (s == 0) ? 0 : (h >> (4 - 2 * s));
            const int i0 = g * (q << 2) + j;
            const int i1 = i0 + q, i2 = i1 + q, i3 = i2 + q;
            const h16x4 A0r = *(const h16x4*)&Lre[i0][c4], A0i = *(const h16x4*)&Lim[i0][c4];
            const h16x4 A1r = *(const h16x4*)&Lre[i1][c4], A1i = *(const h16x4*)&Lim[i1][c4];
            const h16x4 A2r = *(const h16x4*)&Lre[i2][c4], A2i = *(const h16x4*)&Lim[i2][c4];
            const h16x4 A3r = *(const h16x4*)&Lre[i3][c4], A3i = *(const h16x4*)&Lim[i3][c4];
            const int m = j * tw;
            const float w1r = wre[m],     w1i = -wim[m];
            const float w2r = wre[2 * m], w2i = -wim[2 * m];
            const float w3r = wre[3 * m], w3i = -wim[3 * m];
            h16x4 O0r, O0i, O1r, O1i, O2r, O2i, O3r, O3i;
#pragma unroll
            for (int e = 0; e < 4; ++e) {
                float b1r = (float)A1r[e], b1i = (float)A1i[e];
                float b2r = (float)A2r[e], b2i = (float)A2i[e];
                float b3r = (float)A3r[e], b3i = (float)A3i[e];
                if (m) {
                    cmulw(b1r, b1i, w1r, w1i);
                    cmulw(b2r, b2i, w2r, w2i);
                    cmulw(b3r, b3i, w3r, w3i);
                }
                const float a0r = (float)A0r[e], a0i = (float)A0i[e];
                const float u0r = a0r + b2r, u0i = a0i + b2i;
                const float u1r = a0r - b2r, u1i = a0i - b2i;
                const float u2r = b1r + b3r, u2i = b1i + b3i;
                const float dr  = b1r - b3r, di  = b1i - b3i;
                const float u3r = -di, u3i = dr;
                O0r[e] = (_Float16)(u0r + u2r); O0i[e] = (_Float16)(u0i + u2i);
                O1r[e] = (_Float16)(u1r + u3r); O1i[e] = (_Float16)(u1i + u3i);
                O2r[e] = (_Float16)(u0r - u2r); O2i[e] = (_Float16)(u0i - u2i);
                O3r[e] = (_Float16)(u1r - u3r); O3i[e] = (_Float16)(u1i - u3i);
            }
            *(h16x4*)&Lre[i0][c4] = O0r;  *(h16x4*)&Lim[i0][c4] = O0i;
            *(h16x4*)&Lre[i1][c4] = O1r;  *(h16x4*)&Lim[i1][c4] = O1i;
            *(h16x4*)&Lre[i2][c4] = O2r;  *(h16x4*)&Lim[i2][c4] = O2i;
            *(h16x4*)&Lre[i3][c4] = O3r;  *(h16x4*)&Lim[i3][c4] = O3i;
        }
        __syncthreads();
    }
    for (int idx = tid; idx < 2048; idx += 512) {
        const int n1 = idx >> 5, q = idx & 31, blk = q >> 3, f4 = q & 7;
        const int cl = blk * 32 + f4 * 4;
        const h16x4 hr = *(const h16x4*)&Lre[n1][cl];
        float4 o;
        o.x = (float)hr[0]; o.y = (float)hr[1];
        o.z = (float)hr[2]; o.w = (float)hr[3];
        *(float4*)(out + GADDR(n1 * 64 + dg, blk, f4)) = o;
    }
}

// ---------------------------------------------------------------------------
// Weight prep: fold complex 2x2 into W_big bf16 [L][blk][n][k], in d_out.
// ---------------------------------------------------------------------------
extern "C" __global__ void __launch_bounds__(256)
wprep(const float* __restrict__ w1, const float* __restrict__ w2,
      short* __restrict__ wb) {
    const int i4  = blockIdx.x * 256 + threadIdx.x;
    const int k0  = (i4 & 63) * 4;
    const int n   = (i4 >> 6) & 255;
    const int blk = (i4 >> 14) & 3;
    const int L   = i4 >> 16;
    const float* w = L ? w2 : w1;
    bf16x4 pv;
#pragma unroll
    for (int j = 0; j < 4; ++j) {
        const int k = k0 + j;
        float v;
        if (k < 128) {
            v = (n < 128) ? w[blk * 16384 + k * 128 + n]
                          : w[65536 + blk * 16384 + k * 128 + (n - 128)];
        } else {
            v = (n < 128) ? -w[65536 + blk * 16384 + (k - 128) * 128 + n]
                          :  w[blk * 16384 + (k - 128) * 128 + (n - 128)];
        }
        pv[j] = f2bf(v);
    }
    *(bf16x4*)(wb + (size_t)i4 * 4) = pv;
}

// ---------------------------------------------------------------------------
// MFMA block-diagonal complex MLP layer over bf16 planes, in place.
// (unchanged, proven rounds 7-14)
// ---------------------------------------------------------------------------
#define MITER 4

__device__ __forceinline__ void stage_tile(const short* __restrict__ zre,
                                           const short* __restrict__ zim,
                                           char* Abuf, int rowbase, int blk,
                                           int wave, int lane) {
#pragma unroll
    for (int it = 0; it < 4; ++it) {
        const int chunk = wave * 256 + it * 64 + lane;   // 16B chunk id, 0..2047
        const int row   = chunk >> 5;
        const unsigned kbyte = ((unsigned)((chunk & 31) << 4)) ^ ((unsigned)((row & 7) << 4));
        const int k0 = (int)(kbyte >> 1);                // element k, multiple of 8
        const short* src = (k0 < 128) ? zre : zim;
        const size_t g = (size_t)(rowbase + row) * 512 + blk * 128 + (k0 & 127);
        unsigned* lp = (unsigned*)(Abuf + (wave * 4096 + it * 1024));  // wave-uniform
        __builtin_amdgcn_global_load_lds((const unsigned*)(src + g), lp, 16, 0, 0);
    }
}

template<int LAYER>
__global__ void __launch_bounds__(512)
mlp_mfma(short* __restrict__ zre, short* __restrict__ zim,
         const short* __restrict__ wb, const float* __restrict__ bias) {
    __shared__ __align__(16) char As[2][64 * 256 * 2];   // 2 x 32 KB bf16, swizzled

    const int blk  = blockIdx.y;
    const int tid  = threadIdx.x;
    const int wave = tid >> 6;
    const int lane = tid & 63;
    const int lrow = lane & 15;
    const int lk   = lane >> 4;

    bf16x8 Bf[2][8];
#pragma unroll
    for (int nt = 0; nt < 2; ++nt) {
        const int n = wave * 32 + nt * 16 + lrow;
#pragma unroll
        for (int ks = 0; ks < 8; ++ks) {
            Bf[nt][ks] = *(const bf16x8*)(wb + ((size_t)(blk * 256 + n) * 256 + ks * 32 + lk * 8));
        }
    }

    float bv[2];
#pragma unroll
    for (int nt = 0; nt < 2; ++nt) {
        const int n = wave * 32 + nt * 16 + lrow;
        bv[nt] = (n < 128) ? bias[blk * 128 + n] : bias[512 + blk * 128 + (n - 128)];
    }

    stage_tile(zre, zim, As[0], blockIdx.x * MITER * 64, blk, wave, lane);

    for (int t = 0; t < MITER; ++t) {
        __syncthreads();

        if (t + 1 < MITER)
            stage_tile(zre, zim, As[(t + 1) & 1],
                       (blockIdx.x * MITER + t + 1) * 64, blk, wave, lane);

        const char* Ab = As[t & 1];
        const int rowbase = (blockIdx.x * MITER + t) * 64;

        f32x4 acc[4][2];
#pragma unroll
        for (int mt = 0; mt < 4; ++mt)
#pragma unroll
            for (int nt = 0; nt < 2; ++nt)
                acc[mt][nt] = (f32x4){0.f, 0.f, 0.f, 0.f};

#pragma unroll
        for (int ks = 0; ks < 8; ++ks) {
            bf16x8 af[4];
#pragma unroll
            for (int mt = 0; mt < 4; ++mt) {
                const int row = mt * 16 + lrow;
                const int k0  = ks * 32 + lk * 8;
                const unsigned byteoff =
                    ((unsigned)(row * 512 + k0 * 2)) ^ ((unsigned)((row & 7) << 4));
                af[mt] = *(const bf16x8*)(Ab + byteoff);
            }
#pragma unroll
            for (int mt = 0; mt < 4; ++mt)
#pragma unroll
                for (int nt = 0; nt < 2; ++nt)
                    acc[mt][nt] = __builtin_amdgcn_mfma_f32_16x16x32_bf16(
                        af[mt], Bf[nt][ks], acc[mt][nt], 0, 0, 0);
        }

#pragma unroll
        for (int nt = 0; nt < 2; ++nt) {
            const int n = wave * 32 + nt * 16 + lrow;
            short* dst = (n < 128) ? zre : zim;
            const int col = blk * 128 + (n & 127);
#pragma unroll
            for (int mt = 0; mt < 4; ++mt) {
#pragma unroll
                for (int r = 0; r < 4; ++r) {
                    const int row = rowbase + mt * 16 + lk * 4 + r;
                    float v = acc[mt][nt][r] + bv[nt];
                    if (LAYER == 1) {
                        v = fmaxf(v, 0.0f);
                    } else {
                        v = (v > 0.01f) ? v - 0.01f : ((v < -0.01f) ? v + 0.01f : 0.0f);
                    }
                    dst[(size_t)row * 512 + col] = f2bf(v);
                }
            }
        }
    }
}

extern "C" void kernel_launch(void* const* d_in, const int* in_sizes, int n_in,
                              void* d_out, int out_size, void* d_ws, size_t ws_size,
                              hipStream_t stream) {
    const float* x  = (const float*)d_in[0];
    const float* w1 = (const float*)d_in[1];
    const float* w2 = (const float*)d_in[2];
    const float* b1 = (const float*)d_in[3];
    const float* b2 = (const float*)d_in[4];

    float* out = (float*)d_out;
    short* zre = (short*)d_ws;            // bf16 real plane, 32 MiB
    short* zim = zre + 16777216;          // bf16 imag plane, 32 MiB
    short* wb  = (short*)d_out;           // 1 MiB W_big scratch inside d_out
    const size_t WB_L = 4ull * 256 * 256;

    wprep<<<512, 256, 0, stream>>>(w1, w2, wb);

    // forward FFT2 (ortho), radix-4 four-step; fft4+scale fused into pass B
    fft_fwd_a<<<2048, 512, 0, stream>>>(x, zre, zim);
    fft_fwd_b<<<512, 512, 0, stream>>>(zre, zim);

    // block-diagonal complex MLP via MFMA, one dispatch per layer, in place
    mlp_mfma<1><<<dim3(32768 / (64 * MITER), 4), 512, 0, stream>>>(zre, zim, wb, b1);
    mlp_mfma<2><<<dim3(32768 / (64 * MITER), 4), 512, 0, stream>>>(zre, zim, wb + WB_L, b2);

    // inverse FFT2 (ortho), radix-4; fft4_inv+scale fused into pass A
    fft_inv_a<<<512, 512, 0, stream>>>(zre, zim);
    fft_inv_b<<<2048, 512, 0, stream>>>(zre, zim, out);
}

// Round 16
// 218.961 us; speedup vs baseline: 1.0746x; 1.0746x over previous
//
#include <hip/hip_runtime.h>
#include <math.h>

#define TWO_PI 6.283185307179586f

typedef __attribute__((ext_vector_type(8))) short bf16x8;
typedef __attribute__((ext_vector_type(4))) short bf16x4;
typedef __attribute__((ext_vector_type(4))) float f32x4;
typedef __attribute__((ext_vector_type(4))) _Float16 h16x4;
typedef __attribute__((ext_vector_type(8))) _Float16 h16x8;

__device__ __forceinline__ short f2bf(float f) {
    unsigned u = __float_as_uint(f);
    unsigned r = (u + 0x7FFFu + ((u >> 16) & 1u)) >> 16;   // RNE
    return (short)r;
}
__device__ __forceinline__ float bf2f(short s) {
    return __uint_as_float(((unsigned)(unsigned short)s) << 16);
}

// base-4 digit reversal of a 6-bit index (radix-4 FFT output order)
__device__ __forceinline__ int dr4(int s) {
    return ((s & 3) << 4) | (s & 12) | ((s >> 4) & 3);
}

__device__ __forceinline__ void cmulw(float& xr, float& xi, float wr, float wi) {
    const float tr = xr * wr - xi * wi;
    xi = xr * wi + xi * wr;
    xr = tr;
}

// ---------------------------------------------------------------------------
// LDS radix-4 64-point FFT, CHANNEL-VECTORIZED (proven round-14 core):
// thread owns 4 adjacent channels (h16x4 = 8B ds ops) and ONE butterfly per
// stage (h in [0,16)). fp32 compute, fp16 storage. W=136 halfs.
// wtr/wti: W64^m = (cos,-sin)(2pi m/64), m in [0,48).
// ---------------------------------------------------------------------------
template<int W>
__device__ __forceinline__ void fft64_dif4v(_Float16 (*Lre)[W], _Float16 (*Lim)[W],
                                            const float* wtr, const float* wti,
                                            int c4, int h) {
#pragma unroll
    for (int s = 0; s < 3; ++s) {
        const int q  = 16 >> (2 * s);
        const int tw = 1 << (2 * s);
        __syncthreads();
        const int j = h & (q - 1);
        const int g = (s == 0) ? 0 : (h >> (4 - 2 * s));
        const int i0 = g * (q << 2) + j;
        const int i1 = i0 + q, i2 = i1 + q, i3 = i2 + q;
        const h16x4 A0r = *(const h16x4*)&Lre[i0][c4], A0i = *(const h16x4*)&Lim[i0][c4];
        const h16x4 A1r = *(const h16x4*)&Lre[i1][c4], A1i = *(const h16x4*)&Lim[i1][c4];
        const h16x4 A2r = *(const h16x4*)&Lre[i2][c4], A2i = *(const h16x4*)&Lim[i2][c4];
        const h16x4 A3r = *(const h16x4*)&Lre[i3][c4], A3i = *(const h16x4*)&Lim[i3][c4];
        const int m = j * tw;
        const float w1r = wtr[m],     w1i = wti[m];
        const float w2r = wtr[2 * m], w2i = wti[2 * m];
        const float w3r = wtr[3 * m], w3i = wti[3 * m];
        h16x4 O0r, O0i, O1r, O1i, O2r, O2i, O3r, O3i;
#pragma unroll
        for (int e = 0; e < 4; ++e) {
            const float a0r = (float)A0r[e], a0i = (float)A0i[e];
            const float a1r = (float)A1r[e], a1i = (float)A1i[e];
            const float a2r = (float)A2r[e], a2i = (float)A2i[e];
            const float a3r = (float)A3r[e], a3i = (float)A3i[e];
            const float t0r = a0r + a2r, t0i = a0i + a2i;
            const float t2r = a0r - a2r, t2i = a0i - a2i;
            const float t1r = a1r + a3r, t1i = a1i + a3i;
            const float dr  = a1r - a3r, di  = a1i - a3i;
            const float t3r = di, t3i = -dr;                 // -i*(a1-a3)
            O0r[e] = (_Float16)(t0r + t1r);  O0i[e] = (_Float16)(t0i + t1i);
            float y1r = t2r + t3r, y1i = t2i + t3i;
            float y2r = t0r - t1r, y2i = t0i - t1i;
            float y3r = t2r - t3r, y3i = t2i - t3i;
            if (m) {
                cmulw(y1r, y1i, w1r, w1i);
                cmulw(y2r, y2i, w2r, w2i);
                cmulw(y3r, y3i, w3r, w3i);
            }
            O1r[e] = (_Float16)y1r; O1i[e] = (_Float16)y1i;
            O2r[e] = (_Float16)y2r; O2i[e] = (_Float16)y2i;
            O3r[e] = (_Float16)y3r; O3i[e] = (_Float16)y3i;
        }
        *(h16x4*)&Lre[i0][c4] = O0r;  *(h16x4*)&Lim[i0][c4] = O0i;
        *(h16x4*)&Lre[i1][c4] = O1r;  *(h16x4*)&Lim[i1][c4] = O1i;
        *(h16x4*)&Lre[i2][c4] = O2r;  *(h16x4*)&Lim[i2][c4] = O2i;
        *(h16x4*)&Lre[i3][c4] = O3r;  *(h16x4*)&Lim[i3][c4] = O3i;
    }
    __syncthreads();
}

template<int W>
__device__ __forceinline__ void fft64_dit4v(_Float16 (*Lre)[W], _Float16 (*Lim)[W],
                                            const float* wtr, const float* wti,
                                            int c4, int h) {
#pragma unroll
    for (int s = 2; s >= 0; --s) {
        const int q  = 16 >> (2 * s);
        const int tw = 1 << (2 * s);
        __syncthreads();
        const int j = h & (q - 1);
        const int g = (s == 0) ? 0 : (h >> (4 - 2 * s));
        const int i0 = g * (q << 2) + j;
        const int i1 = i0 + q, i2 = i1 + q, i3 = i2 + q;
        const h16x4 A0r = *(const h16x4*)&Lre[i0][c4], A0i = *(const h16x4*)&Lim[i0][c4];
        const h16x4 A1r = *(const h16x4*)&Lre[i1][c4], A1i = *(const h16x4*)&Lim[i1][c4];
        const h16x4 A2r = *(const h16x4*)&Lre[i2][c4], A2i = *(const h16x4*)&Lim[i2][c4];
        const h16x4 A3r = *(const h16x4*)&Lre[i3][c4], A3i = *(const h16x4*)&Lim[i3][c4];
        const int m = j * tw;
        const float w1r = wtr[m],     w1i = -wti[m];         // conj
        const float w2r = wtr[2 * m], w2i = -wti[2 * m];
        const float w3r = wtr[3 * m], w3i = -wti[3 * m];
        h16x4 O0r, O0i, O1r, O1i, O2r, O2i, O3r, O3i;
#pragma unroll
        for (int e = 0; e < 4; ++e) {
            float b1r = (float)A1r[e], b1i = (float)A1i[e];
            float b2r = (float)A2r[e], b2i = (float)A2i[e];
            float b3r = (float)A3r[e], b3i = (float)A3i[e];
            if (m) {
                cmulw(b1r, b1i, w1r, w1i);
                cmulw(b2r, b2i, w2r, w2i);
                cmulw(b3r, b3i, w3r, w3i);
            }
            const float a0r = (float)A0r[e], a0i = (float)A0i[e];
            const float u0r = a0r + b2r, u0i = a0i + b2i;
            const float u1r = a0r - b2r, u1i = a0i - b2i;
            const float u2r = b1r + b3r, u2i = b1i + b3i;
            const float dr  = b1r - b3r, di  = b1i - b3i;
            const float u3r = -di, u3i = dr;                 // +i*(b1-b3)
            O0r[e] = (_Float16)(u0r + u2r); O0i[e] = (_Float16)(u0i + u2i);
            O1r[e] = (_Float16)(u1r + u3r); O1i[e] = (_Float16)(u1i + u3i);
            O2r[e] = (_Float16)(u0r - u2r); O2i[e] = (_Float16)(u0i - u2i);
            O3r[e] = (_Float16)(u1r - u3r); O3i[e] = (_Float16)(u1i - u3i);
        }
        *(h16x4*)&Lre[i0][c4] = O0r;  *(h16x4*)&Lim[i0][c4] = O0i;
        *(h16x4*)&Lre[i1][c4] = O1r;  *(h16x4*)&Lim[i1][c4] = O1i;
        *(h16x4*)&Lre[i2][c4] = O2r;  *(h16x4*)&Lim[i2][c4] = O2i;
        *(h16x4*)&Lre[i3][c4] = O3r;  *(h16x4*)&Lim[i3][c4] = O3i;
    }
    __syncthreads();
}

#define DECODE_BCT() \
    const int b  = blockIdx.x >> 8; \
    const int dg = (blockIdx.x >> 2) & 63; \
    const int ct = blockIdx.x & 3;

#define GADDR(slot, blk, f4) \
    (((size_t)(b * 4096 + (slot)) * 512) + (size_t)((blk) * 128 + ct * 32 + (f4) * 4))

#define GADDR8(slot, blk, e8) \
    (((size_t)(b * 4096 + (slot)) * 512) + (size_t)((blk) * 128 + ct * 32 + (e8) * 8))

#define SETUP_TABLE48() \
    if (tid < 48) { \
        float s_, c_; \
        sincosf(TWO_PI * (float)tid / 64.0f, &s_, &c_); \
        wre[tid] = c_; wim[tid] = -s_; \
    }

// ---- forward pass A: FFT over n1, twiddle, FUSED fft4_fwd (x1/128),
// x fp32 -> z bf16. (fft2 is separable: FFT_4 on the block axis commutes
// with both n-passes, so it can live here instead of pass B.)
extern "C" __global__ void __launch_bounds__(512)
fft_fwd_a(const float* __restrict__ x, short* __restrict__ zre, short* __restrict__ zim) {
    __shared__ __align__(16) _Float16 Lre[64][136];
    __shared__ __align__(16) _Float16 Lim[64][136];
    __shared__ float wre[48], wim[48];
    __shared__ float twr[64], twi[64];
    const int tid = threadIdx.x;
    SETUP_TABLE48();
    DECODE_BCT();   // dg = n2
    if (tid >= 64 && tid < 128) {
        const int s1 = tid - 64;
        float sn, cs;
        sincosf(-(TWO_PI / 4096.0f) * (float)(dg * dr4(s1)), &sn, &cs);
        twr[s1] = cs; twi[s1] = sn;
    }
    for (int idx = tid; idx < 2048; idx += 512) {
        const int n1 = idx >> 5, q = idx & 31, blk = q >> 3, f4 = q & 7;
        const int cl = blk * 32 + f4 * 4;
        const float4 v = *(const float4*)(x + GADDR(n1 * 64 + dg, blk, f4));
        h16x4 hv, hz;
        hv[0] = (_Float16)v.x; hv[1] = (_Float16)v.y;
        hv[2] = (_Float16)v.z; hv[3] = (_Float16)v.w;
        hz[0] = (_Float16)0.f; hz[1] = (_Float16)0.f;
        hz[2] = (_Float16)0.f; hz[3] = (_Float16)0.f;
        *(h16x4*)&Lre[n1][cl] = hv;
        *(h16x4*)&Lim[n1][cl] = hz;
    }
    fft64_dif4v<136>(Lre, Lim, wre, wim, (tid & 31) * 4, tid >> 5);
    // twiddle + fft4 across blocks + 1/128 + store: item = (s1, f4), 1/thread
    {
        const int s1 = tid >> 3, f4 = tid & 7;
        const float cs = twr[s1], sn = twi[s1];
        f32x4 r[4], m[4];
#pragma unroll
        for (int blk = 0; blk < 4; ++blk) {
            const int cl = blk * 32 + f4 * 4;
            const h16x4 hr = *(const h16x4*)&Lre[s1][cl];
            const h16x4 hi = *(const h16x4*)&Lim[s1][cl];
#pragma unroll
            for (int e = 0; e < 4; ++e) {
                const float vr = (float)hr[e], vi = (float)hi[e];
                r[blk][e] = vr * cs - vi * sn;
                m[blk][e] = vr * sn + vi * cs;
            }
        }
        const float sc = 1.0f / 128.0f;
        f32x4 yr[4], ym[4];
#pragma unroll
        for (int e = 0; e < 4; ++e) {
            const float r0 = r[0][e], r1 = r[1][e], r2 = r[2][e], r3 = r[3][e];
            const float m0 = m[0][e], m1 = m[1][e], m2 = m[2][e], m3 = m[3][e];
            yr[0][e] = (r0 + r1 + r2 + r3) * sc;  ym[0][e] = (m0 + m1 + m2 + m3) * sc;
            yr[1][e] = (r0 + m1 - r2 - m3) * sc;  ym[1][e] = (m0 - r1 - m2 + r3) * sc;
            yr[2][e] = (r0 - r1 + r2 - r3) * sc;  ym[2][e] = (m0 - m1 + m2 - m3) * sc;
            yr[3][e] = (r0 - m1 - r2 + m3) * sc;  ym[3][e] = (m0 + r1 - m2 - r3) * sc;
        }
#pragma unroll
        for (int blk = 0; blk < 4; ++blk) {
            bf16x4 pr, pi;
#pragma unroll
            for (int e = 0; e < 4; ++e) {
                pr[e] = f2bf(yr[blk][e]);
                pi[e] = f2bf(ym[blk][e]);
            }
            const size_t g = GADDR(s1 * 64 + dg, blk, f4);
            *(bf16x4*)(zre + g) = pr;
            *(bf16x4*)(zim + g) = pi;
        }
    }
}

// ---- forward pass B: FFT over n2 only (fft4 moved to pass A) ----
extern "C" __global__ void __launch_bounds__(512)
fft_fwd_b(short* __restrict__ zre, short* __restrict__ zim) {
    __shared__ __align__(16) _Float16 Lre[64][136];
    __shared__ __align__(16) _Float16 Lim[64][136];
    __shared__ float wre[48], wim[48];
    const int tid = threadIdx.x;
    SETUP_TABLE48();
    DECODE_BCT();   // dg = s1
    for (int idx = tid; idx < 1024; idx += 512) {
        const int n2 = idx >> 4, q = idx & 15, blk = q >> 2, e8 = q & 3;
        const int cl = blk * 32 + e8 * 8;
        const size_t g = GADDR8(dg * 64 + n2, blk, e8);
        const bf16x8 vr = *(const bf16x8*)(zre + g);
        const bf16x8 vi = *(const bf16x8*)(zim + g);
        h16x8 hr, hi;
#pragma unroll
        for (int i = 0; i < 8; ++i) {
            hr[i] = (_Float16)bf2f(vr[i]);
            hi[i] = (_Float16)bf2f(vi[i]);
        }
        *(h16x8*)&Lre[n2][cl] = hr;
        *(h16x8*)&Lim[n2][cl] = hi;
    }
    fft64_dif4v<136>(Lre, Lim, wre, wim, (tid & 31) * 4, tid >> 5);
    for (int idx = tid; idx < 1024; idx += 512) {
        const int s2 = idx >> 4, q = idx & 15, blk = q >> 2, e8 = q & 3;
        const int cl = blk * 32 + e8 * 8;
        const h16x8 hr = *(const h16x8*)&Lre[s2][cl];
        const h16x8 hi = *(const h16x8*)&Lim[s2][cl];
        bf16x8 pr, pi;
#pragma unroll
        for (int i = 0; i < 8; ++i) {
            pr[i] = f2bf((float)hr[i]);
            pi[i] = f2bf((float)hi[i]);
        }
        const size_t g = GADDR8(dg * 64 + s2, blk, e8);
        *(bf16x8*)(zre + g) = pr;
        *(bf16x8*)(zim + g) = pi;
    }
}

// ---- inverse pass A: inverse FFT over k2 + twiddle (ifft4 moved to pass B)
extern "C" __global__ void __launch_bounds__(512)
fft_inv_a(short* __restrict__ zre, short* __restrict__ zim) {
    __shared__ __align__(16) _Float16 Lre[64][136];
    __shared__ __align__(16) _Float16 Lim[64][136];
    __shared__ float wre[48], wim[48];
    __shared__ float twr[64], twi[64];
    const int tid = threadIdx.x;
    SETUP_TABLE48();
    DECODE_BCT();   // dg = s1
    if (tid >= 64 && tid < 128) {
        const int n2 = tid - 64;
        float sn, cs;
        sincosf((TWO_PI / 4096.0f) * (float)(n2 * dr4(dg)), &sn, &cs);
        twr[n2] = cs; twi[n2] = sn;
    }
    for (int idx = tid; idx < 1024; idx += 512) {
        const int s2 = idx >> 4, q = idx & 15, blk = q >> 2, e8 = q & 3;
        const int cl = blk * 32 + e8 * 8;
        const size_t g = GADDR8(dg * 64 + s2, blk, e8);
        const bf16x8 vr = *(const bf16x8*)(zre + g);
        const bf16x8 vi = *(const bf16x8*)(zim + g);
        h16x8 hr, hi;
#pragma unroll
        for (int i = 0; i < 8; ++i) {
            hr[i] = (_Float16)bf2f(vr[i]);
            hi[i] = (_Float16)bf2f(vi[i]);
        }
        *(h16x8*)&Lre[s2][cl] = hr;
        *(h16x8*)&Lim[s2][cl] = hi;
    }
    fft64_dit4v<136>(Lre, Lim, wre, wim, (tid & 31) * 4, tid >> 5);
    for (int idx = tid; idx < 2048; idx += 512) {
        const int n2 = idx >> 5, q = idx & 31, blk = q >> 3, f4 = q & 7;
        const int cl = blk * 32 + f4 * 4;
        const float cs = twr[n2], sn = twi[n2];
        const h16x4 hr = *(const h16x4*)&Lre[n2][cl];
        const h16x4 hi = *(const h16x4*)&Lim[n2][cl];
        bf16x4 pr, pi;
#pragma unroll
        for (int i = 0; i < 4; ++i) {
            const float vr = (float)hr[i], vi = (float)hi[i];
            pr[i] = f2bf(vr * cs - vi * sn);
            pi[i] = f2bf(vr * sn + vi * cs);
        }
        const size_t g = GADDR(dg * 64 + n2, blk, f4);
        *(bf16x4*)(zre + g) = pr;
        *(bf16x4*)(zim + g) = pi;
    }
}

// ---- inverse pass B: FUSED ifft4 (x1/128) on load, inverse FFT over k1,
// write REAL fp32 into d_out.
extern "C" __global__ void __launch_bounds__(512)
fft_inv_b(const short* __restrict__ zre, const short* __restrict__ zim,
          float* __restrict__ out) {
    __shared__ __align__(16) _Float16 Lre[64][136];
    __shared__ __align__(16) _Float16 Lim[64][136];
    __shared__ float wre[48], wim[48];
    const int tid = threadIdx.x;
    SETUP_TABLE48();
    DECODE_BCT();   // dg = n2
    // load + inverse fft4 + 1/128 -> LDS fp16: item = (s1, f4), 1/thread
    {
        const int s1 = tid >> 3, f4 = tid & 7;
        f32x4 r[4], m[4];
#pragma unroll
        for (int blk = 0; blk < 4; ++blk) {
            const size_t g = GADDR(s1 * 64 + dg, blk, f4);
            const bf16x4 vr = *(const bf16x4*)(zre + g);
            const bf16x4 vi = *(const bf16x4*)(zim + g);
#pragma unroll
            for (int e = 0; e < 4; ++e) {
                r[blk][e] = bf2f(vr[e]);
                m[blk][e] = bf2f(vi[e]);
            }
        }
        const float sc = 1.0f / 128.0f;
        f32x4 yr[4], ym[4];
#pragma unroll
        for (int e = 0; e < 4; ++e) {
            const float r0 = r[0][e], r1 = r[1][e], r2 = r[2][e], r3 = r[3][e];
            const float m0 = m[0][e], m1 = m[1][e], m2 = m[2][e], m3 = m[3][e];
            yr[0][e] = (r0 + r1 + r2 + r3) * sc;  ym[0][e] = (m0 + m1 + m2 + m3) * sc;
            yr[1][e] = (r0 - m1 - r2 + m3) * sc;  ym[1][e] = (m0 + r1 - m2 - r3) * sc;
            yr[2][e] = (r0 - r1 + r2 - r3) * sc;  ym[2][e] = (m0 - m1 + m2 - m3) * sc;
            yr[3][e] = (r0 + m1 - r2 - m3) * sc;  ym[3][e] = (m0 - r1 - m2 + r3) * sc;
        }
#pragma unroll
        for (int blk = 0; blk < 4; ++blk) {
            const int cl = blk * 32 + f4 * 4;
            h16x4 hr, hi;
#pragma unroll
            for (int e = 0; e < 4; ++e) {
                hr[e] = (_Float16)yr[blk][e];
                hi[e] = (_Float16)ym[blk][e];
            }
            *(h16x4*)&Lre[s1][cl] = hr;
            *(h16x4*)&Lim[s1][cl] = hi;
        }
    }
    fft64_dit4v<136>(Lre, Lim, wre, wim, (tid & 31) * 4, tid >> 5);
    for (int idx = tid; idx < 2048; idx += 512) {
        const int n1 = idx >> 5, q = idx & 31, blk = q >> 3, f4 = q & 7;
        const int cl = blk * 32 + f4 * 4;
        const h16x4 hr = *(const h16x4*)&Lre[n1][cl];
        float4 o;
        o.x = (float)hr[0]; o.y = (float)hr[1];
        o.z = (float)hr[2]; o.w = (float)hr[3];
        *(float4*)(out + GADDR(n1 * 64 + dg, blk, f4)) = o;
    }
}

// ---------------------------------------------------------------------------
// Weight prep: fold complex 2x2 into W_big bf16 [L][blk][n][k], in d_out.
// ---------------------------------------------------------------------------
extern "C" __global__ void __launch_bounds__(256)
wprep(const float* __restrict__ w1, const float* __restrict__ w2,
      short* __restrict__ wb) {
    const int i4  = blockIdx.x * 256 + threadIdx.x;
    const int k0  = (i4 & 63) * 4;
    const int n   = (i4 >> 6) & 255;
    const int blk = (i4 >> 14) & 3;
    const int L   = i4 >> 16;
    const float* w = L ? w2 : w1;
    bf16x4 pv;
#pragma unroll
    for (int j = 0; j < 4; ++j) {
        const int k = k0 + j;
        float v;
        if (k < 128) {
            v = (n < 128) ? w[blk * 16384 + k * 128 + n]
                          : w[65536 + blk * 16384 + k * 128 + (n - 128)];
        } else {
            v = (n < 128) ? -w[65536 + blk * 16384 + (k - 128) * 128 + n]
                          :  w[blk * 16384 + (k - 128) * 128 + (n - 128)];
        }
        pv[j] = f2bf(v);
    }
    *(bf16x4*)(wb + (size_t)i4 * 4) = pv;
}

// ---------------------------------------------------------------------------
// MFMA block-diagonal complex MLP layer over bf16 planes, in place.
// (unchanged, proven rounds 7-15)
// ---------------------------------------------------------------------------
#define MITER 4

__device__ __forceinline__ void stage_tile(const short* __restrict__ zre,
                                           const short* __restrict__ zim,
                                           char* Abuf, int rowbase, int blk,
                                           int wave, int lane) {
#pragma unroll
    for (int it = 0; it < 4; ++it) {
        const int chunk = wave * 256 + it * 64 + lane;   // 16B chunk id, 0..2047
        const int row   = chunk >> 5;
        const unsigned kbyte = ((unsigned)((chunk & 31) << 4)) ^ ((unsigned)((row & 7) << 4));
        const int k0 = (int)(kbyte >> 1);                // element k, multiple of 8
        const short* src = (k0 < 128) ? zre : zim;
        const size_t g = (size_t)(rowbase + row) * 512 + blk * 128 + (k0 & 127);
        unsigned* lp = (unsigned*)(Abuf + (wave * 4096 + it * 1024));  // wave-uniform
        __builtin_amdgcn_global_load_lds((const unsigned*)(src + g), lp, 16, 0, 0);
    }
}

template<int LAYER>
__global__ void __launch_bounds__(512)
mlp_mfma(short* __restrict__ zre, short* __restrict__ zim,
         const short* __restrict__ wb, const float* __restrict__ bias) {
    __shared__ __align__(16) char As[2][64 * 256 * 2];   // 2 x 32 KB bf16, swizzled

    const int blk  = blockIdx.y;
    const int tid  = threadIdx.x;
    const int wave = tid >> 6;
    const int lane = tid & 63;
    const int lrow = lane & 15;
    const int lk   = lane >> 4;

    bf16x8 Bf[2][8];
#pragma unroll
    for (int nt = 0; nt < 2; ++nt) {
        const int n = wave * 32 + nt * 16 + lrow;
#pragma unroll
        for (int ks = 0; ks < 8; ++ks) {
            Bf[nt][ks] = *(const bf16x8*)(wb + ((size_t)(blk * 256 + n) * 256 + ks * 32 + lk * 8));
        }
    }

    float bv[2];
#pragma unroll
    for (int nt = 0; nt < 2; ++nt) {
        const int n = wave * 32 + nt * 16 + lrow;
        bv[nt] = (n < 128) ? bias[blk * 128 + n] : bias[512 + blk * 128 + (n - 128)];
    }

    stage_tile(zre, zim, As[0], blockIdx.x * MITER * 64, blk, wave, lane);

    for (int t = 0; t < MITER; ++t) {
        __syncthreads();

        if (t + 1 < MITER)
            stage_tile(zre, zim, As[(t + 1) & 1],
                       (blockIdx.x * MITER + t + 1) * 64, blk, wave, lane);

        const char* Ab = As[t & 1];
        const int rowbase = (blockIdx.x * MITER + t) * 64;

        f32x4 acc[4][2];
#pragma unroll
        for (int mt = 0; mt < 4; ++mt)
#pragma unroll
            for (int nt = 0; nt < 2; ++nt)
                acc[mt][nt] = (f32x4){0.f, 0.f, 0.f, 0.f};

#pragma unroll
        for (int ks = 0; ks < 8; ++ks) {
            bf16x8 af[4];
#pragma unroll
            for (int mt = 0; mt < 4; ++mt) {
                const int row = mt * 16 + lrow;
                const int k0  = ks * 32 + lk * 8;
                const unsigned byteoff =
                    ((unsigned)(row * 512 + k0 * 2)) ^ ((unsigned)((row & 7) << 4));
                af[mt] = *(const bf16x8*)(Ab + byteoff);
            }
#pragma unroll
            for (int mt = 0; mt < 4; ++mt)
#pragma unroll
                for (int nt = 0; nt < 2; ++nt)
                    acc[mt][nt] = __builtin_amdgcn_mfma_f32_16x16x32_bf16(
                        af[mt], Bf[nt][ks], acc[mt][nt], 0, 0, 0);
        }

#pragma unroll
        for (int nt = 0; nt < 2; ++nt) {
            const int n = wave * 32 + nt * 16 + lrow;
            short* dst = (n < 128) ? zre : zim;
            const int col = blk * 128 + (n & 127);
#pragma unroll
            for (int mt = 0; mt < 4; ++mt) {
#pragma unroll
                for (int r = 0; r < 4; ++r) {
                    const int row = rowbase + mt * 16 + lk * 4 + r;
                    float v = acc[mt][nt][r] + bv[nt];
                    if (LAYER == 1) {
                        v = fmaxf(v, 0.0f);
                    } else {
                        v = (v > 0.01f) ? v - 0.01f : ((v < -0.01f) ? v + 0.01f : 0.0f);
                    }
                    dst[(size_t)row * 512 + col] = f2bf(v);
                }
            }
        }
    }
}

extern "C" void kernel_launch(void* const* d_in, const int* in_sizes, int n_in,
                              void* d_out, int out_size, void* d_ws, size_t ws_size,
                              hipStream_t stream) {
    const float* x  = (const float*)d_in[0];
    const float* w1 = (const float*)d_in[1];
    const float* w2 = (const float*)d_in[2];
    const float* b1 = (const float*)d_in[3];
    const float* b2 = (const float*)d_in[4];

    float* out = (float*)d_out;
    short* zre = (short*)d_ws;            // bf16 real plane, 32 MiB
    short* zim = zre + 16777216;          // bf16 imag plane, 32 MiB
    short* wb  = (short*)d_out;           // 1 MiB W_big scratch inside d_out
    const size_t WB_L = 4ull * 256 * 256;

    wprep<<<512, 256, 0, stream>>>(w1, w2, wb);

    // forward FFT2 (ortho), radix-4 four-step; fft4+scale fused into pass A
    fft_fwd_a<<<2048, 512, 0, stream>>>(x, zre, zim);
    fft_fwd_b<<<2048, 512, 0, stream>>>(zre, zim);

    // block-diagonal complex MLP via MFMA, one dispatch per layer, in place
    mlp_mfma<1><<<dim3(32768 / (64 * MITER), 4), 512, 0, stream>>>(zre, zim, wb, b1);
    mlp_mfma<2><<<dim3(32768 / (64 * MITER), 4), 512, 0, stream>>>(zre, zim, wb + WB_L, b2);

    // inverse FFT2 (ortho), radix-4; ifft4+scale fused into pass B
    fft_inv_a<<<2048, 512, 0, stream>>>(zre, zim);
    fft_inv_b<<<2048, 512, 0, stream>>>(zre, zim, out);
}